// Round 4
// baseline (145.384 us; speedup 1.0000x reference)
//
#include <hip/hip_runtime.h>

typedef __attribute__((ext_vector_type(8))) short short8;
typedef __attribute__((ext_vector_type(4))) short short4v;
typedef __attribute__((ext_vector_type(4))) float f32x4;
typedef __attribute__((ext_vector_type(4))) int i32x4;

#define NN 8192
#define ALPHA 0.2f

__device__ __forceinline__ float bf16_to_f32(unsigned short h) {
    union { unsigned int u; float f; } c;
    c.u = ((unsigned int)h) << 16;
    return c.f;
}
__device__ __forceinline__ unsigned short f32_to_bf16(float f) {
    union { float f; unsigned int u; } c;
    c.f = f;
    unsigned int r = (c.u + 0x7FFFu + ((c.u >> 16) & 1u)) >> 16;
    return (unsigned short)r;
}

// ---------------- kernel 0: probe input dtype -------------------------------
__global__ void gat_probe_dtype(const unsigned short* __restrict__ x16, int* flag) {
    __shared__ int cnts[256];
    int tid = threadIdx.x;
    int cnt = 0;
    for (int i = tid; i < 16384; i += 256) {
        float v = bf16_to_f32(x16[i]);
        float a = fabsf(v);
        if (a > 1e-6f && a < 64.0f) cnt++;   // false for NaN too
    }
    cnts[tid] = cnt;
    __syncthreads();
    for (int s = 128; s > 0; s >>= 1) {
        if (tid < s) cnts[tid] += cnts[tid + s];
        __syncthreads();
    }
    if (tid == 0) *flag = (cnts[0] > 13000) ? 1 : 0;
}

// ---------------- kernel 1: convert inputs to ws copies (vectorized) --------
__global__ void gat_convert(const void* __restrict__ Xv, const void* __restrict__ Wv,
                            const void* __restrict__ bv, const void* __restrict__ asv,
                            const void* __restrict__ arv,
                            short* __restrict__ Xb, short* __restrict__ Wb,
                            float* __restrict__ bF, float* __restrict__ asF,
                            float* __restrict__ arF, const int* __restrict__ flag) {
    const int GX = NN * 256 / 8;      // short8 groups in X
    const int GW = 256 * 256 / 8;     // short8 groups in W
    const int isBf = *flag;
    const int idx = blockIdx.x * blockDim.x + threadIdx.x;
    const int stride = gridDim.x * blockDim.x;
    for (int i = idx; i < GX + GW; i += stride) {
        const void* src = (i < GX) ? Xv : Wv;
        short* dst = (i < GX) ? Xb : Wb;
        int g = (i < GX) ? i : i - GX;
        short8 o;
        if (isBf) {
            o = ((const short8*)src)[g];
        } else {
            f32x4 a = ((const f32x4*)src)[2 * g];
            f32x4 b = ((const f32x4*)src)[2 * g + 1];
#pragma unroll
            for (int j = 0; j < 4; j++) {
                o[j] = (short)f32_to_bf16(a[j]);
                o[4 + j] = (short)f32_to_bf16(b[j]);
            }
        }
        ((short8*)dst)[g] = o;
    }
    if (idx < 768) {
        int which = idx >> 8;
        int k = idx & 255;
        const void* src = (which == 0) ? bv : (which == 1) ? asv : arv;
        float v = isBf ? bf16_to_f32(((const unsigned short*)src)[k])
                       : ((const float*)src)[k];
        float* dst = (which == 0) ? bF : (which == 1) ? asF : arF;
        dst[k] = v;
    }
}

// ---------------- kernel 2: H_in = X*W^T + b -> Gt, s, r ---------------------
__global__ __launch_bounds__(128) void gat_gemm1(
    const short* __restrict__ Xb, const short* __restrict__ Wb,
    const float* __restrict__ bF, const float* __restrict__ asF,
    const float* __restrict__ arF,
    short* __restrict__ Gt, float* __restrict__ sOut, float* __restrict__ rOut) {
    const int tid = threadIdx.x;
    const int wave = tid >> 6, lane = tid & 63;
    const int l15 = lane & 15, lhi = lane >> 4;
    const int rowBase = blockIdx.x * 32 + wave * 16;

    f32x4 acc[16];
#pragma unroll
    for (int n = 0; n < 16; n++) acc[n] = (f32x4){0.f, 0.f, 0.f, 0.f};

    const short8* Xrow = (const short8*)(Xb + (size_t)(rowBase + l15) * 256);
#pragma unroll
    for (int ks = 0; ks < 8; ks++) {            // K = 256 in steps of 32
        short8 a = Xrow[ks * 4 + lhi];
#pragma unroll
        for (int n = 0; n < 16; n++) {
            const short8* Wrow = (const short8*)(Wb + (size_t)(n * 16 + l15) * 256);
            short8 bf = Wrow[ks * 4 + lhi];
            acc[n] = __builtin_amdgcn_mfma_f32_16x16x32_bf16(a, bf, acc[n], 0, 0, 0);
        }
    }

    float sPart[4] = {0.f, 0.f, 0.f, 0.f};
    float rPart[4] = {0.f, 0.f, 0.f, 0.f};
    float g[4][4];
#pragma unroll
    for (int na = 0; na < 4; na++)
#pragma unroll
        for (int q = 0; q < 4; q++) g[na][q] = 0.f;

#pragma unroll
    for (int n = 0; n < 16; n++) {
        int col = n * 16 + l15;
        float bias = bF[col], asc = asF[col], arc = arF[col];
#pragma unroll
        for (int q = 0; q < 4; q++) {
            float h = acc[n][q] + bias;         // D: row=lhi*4+q, col=l15
            sPart[q] += h * asc;
            rPart[q] += h * arc;
            g[n & 3][q] += h;                   // head-sum
        }
    }
#pragma unroll
    for (int na = 0; na < 4; na++) {
        short4v pk;
#pragma unroll
        for (int q = 0; q < 4; q++) pk[q] = (short)f32_to_bf16(g[na][q]);
        *(short4v*)(Gt + (size_t)(na * 16 + l15) * NN + rowBase + lhi * 4) = pk;
    }

#pragma unroll
    for (int m = 1; m <= 8; m <<= 1) {
#pragma unroll
        for (int q = 0; q < 4; q++) {
            sPart[q] += __shfl_xor(sPart[q], m, 64);
            rPart[q] += __shfl_xor(rPart[q], m, 64);
        }
    }
    if (l15 == 0) {
#pragma unroll
        for (int q = 0; q < 4; q++) {
            int row = rowBase + lhi * 4 + q;
            sOut[row] = sPart[q];
            rOut[row] = rPart[q];
        }
    }
}

// ---------------- kernel 3: fused masked-softmax PV (v4) --------------------
// Grid = 256 row-blocks x 4 K-slices, 256 thr. Wave (wm,wk): 16 rows, 1024 k.
// P generated DIRECTLY in MFMA A-fragment layout (no LDS at all): lane
// (l15,lhi) computes P[row=l15][k=k0+ksx*32+lhi*8+j] from its own A ints.
// A loads double-buffered (prefetch t+1 before computing t). Row-denominators
// via a 5th MFMA against a ones-in-column-0 B fragment. Partial outputs to
// accP[8][N][64], denP[8][N]; no atomics, no syncs.

#define GAT_LOADA(D00, D01, D10, D11, T_)                                    \
    {                                                                        \
        const int* p_ = ab + (size_t)(ksBase + (T_)) * 64;                   \
        D00 = *(const i32x4*)(p_);                                          \
        D01 = *(const i32x4*)(p_ + 4);                                      \
        D10 = *(const i32x4*)(p_ + 32);                                     \
        D11 = *(const i32x4*)(p_ + 36);                                     \
    }

#define GAT_HALF(K0_, KS_, AV0, AV1)                                         \
    {                                                                        \
        f32x4 r0 = *(const f32x4*)(rvb + (K0_) + (KS_)*32);                  \
        f32x4 r1 = *(const f32x4*)(rvb + (K0_) + (KS_)*32 + 4);              \
        short8 pa;                                                           \
        _Pragma("unroll") for (int j = 0; j < 4; j++) {                      \
            float x = sMine + r0[j];                                         \
            x = fmaxf(x, ALPHA * x);                                         \
            float e = __expf(x);                                             \
            pa[j] = (short)f32_to_bf16((AV0)[j] ? e : 0.f);                  \
        }                                                                    \
        _Pragma("unroll") for (int j = 0; j < 4; j++) {                      \
            float x = sMine + r1[j];                                         \
            x = fmaxf(x, ALPHA * x);                                         \
            float e = __expf(x);                                             \
            pa[4 + j] = (short)f32_to_bf16((AV1)[j] ? e : 0.f);              \
        }                                                                    \
        _Pragma("unroll") for (int n = 0; n < 4; n++) {                      \
            short8 bfr = *(const short8*)(gbase + (size_t)n * 16 * NN +      \
                                          (K0_) + (KS_)*32);                 \
            acc[n] = __builtin_amdgcn_mfma_f32_16x16x32_bf16(pa, bfr,        \
                                                             acc[n], 0, 0, 0); \
        }                                                                    \
        acc[4] = __builtin_amdgcn_mfma_f32_16x16x32_bf16(pa, onesB,          \
                                                         acc[4], 0, 0, 0);  \
    }

#define GAT_BODY(T_, A00, A01, A10, A11)                                     \
    {                                                                        \
        const int k0_ = (ksBase + (T_)) * 64;                                \
        GAT_HALF(k0_, 0, A00, A01);                                          \
        GAT_HALF(k0_, 1, A10, A11);                                          \
    }

__global__ __launch_bounds__(256, 4) void gat_pv4(
    const int* __restrict__ A, const short* __restrict__ Gt,
    const float* __restrict__ sV, const float* __restrict__ rV,
    float* __restrict__ accP, float* __restrict__ denP) {
    const int tid = threadIdx.x;
    const int wave = tid >> 6, lane = tid & 63;
    const int l15 = lane & 15, lhi = lane >> 4;
    const int wm = wave >> 1, wk = wave & 1;
    const int rb = blockIdx.x >> 2;
    const int ks = blockIdx.x & 3;
    const int i0 = rb * 32;
    const int sk = ks * 2 + wk;
    const int rowTop = i0 + wm * 16;
    const int ksBase = ks * 32 + wk * 16;       // first 64-k tile index

    const float sMine = sV[rowTop + l15];
    const int* ab = A + (size_t)(rowTop + l15) * NN + lhi * 8;
    const float* rvb = rV + lhi * 8;
    const short* gbase = Gt + (size_t)l15 * NN + lhi * 8;

    short8 onesB;
#pragma unroll
    for (int j = 0; j < 8; j++) onesB[j] = (l15 == 0) ? (short)0x3F80 : (short)0;

    f32x4 acc[5];
#pragma unroll
    for (int n = 0; n < 5; n++) acc[n] = (f32x4){0.f, 0.f, 0.f, 0.f};

    i32x4 a00, a01, a10, a11, b00, b01, b10, b11;
    GAT_LOADA(a00, a01, a10, a11, 0);
    for (int t = 0; t < 16; t += 2) {
        GAT_LOADA(b00, b01, b10, b11, t + 1);
        GAT_BODY(t, a00, a01, a10, a11);
        {
            const int t2 = (t + 2 < 16) ? t + 2 : 15;   // clamp: redundant reload at tail
            GAT_LOADA(a00, a01, a10, a11, t2);
        }
        GAT_BODY(t + 1, b00, b01, b10, b11);
    }

    // partial accumulator store (disjoint per slice, coalesced 64B/quarter)
    float* aout = accP + (size_t)sk * NN * 64;
#pragma unroll
    for (int n = 0; n < 4; n++)
#pragma unroll
        for (int q = 0; q < 4; q++)
            aout[(size_t)(rowTop + lhi * 4 + q) * 64 + n * 16 + l15] = acc[n][q];

    // denominators came out of the ones-column MFMA: col 0 lives in l15==0
    if (l15 == 0) {
#pragma unroll
        for (int q = 0; q < 4; q++)
            denP[(size_t)sk * NN + rowTop + lhi * 4 + q] = acc[4][q];
    }
}

// ---------------- kernel 4: sum 8 partials, divide, cast --------------------
__global__ void gat_final(const float* __restrict__ accP, const float* __restrict__ denP,
                          const int* __restrict__ flag, void* __restrict__ outP) {
    int idx = blockIdx.x * blockDim.x + threadIdx.x;  // one f32x4 group
    if (idx >= NN * 16) return;
    int row = idx >> 4;
    float den = 0.f;
    f32x4 v = (f32x4){0.f, 0.f, 0.f, 0.f};
#pragma unroll
    for (int sk = 0; sk < 8; sk++) {
        den += denP[(size_t)sk * NN + row];
        f32x4 a = *((const f32x4*)(accP + (size_t)sk * NN * 64) + idx);
        v.x += a.x; v.y += a.y; v.z += a.z; v.w += a.w;
    }
    float inv = 1.0f / den;
    v.x *= inv; v.y *= inv; v.z *= inv; v.w *= inv;
    if (*flag) {
        short4v pk;
#pragma unroll
        for (int j = 0; j < 4; j++) pk[j] = (short)f32_to_bf16(v[j]);
        *((short4v*)outP + idx) = pk;
    } else {
        *((f32x4*)outP + idx) = v;
    }
}

// ---------------- launch -----------------------------------------------------
extern "C" void kernel_launch(void* const* d_in, const int* in_sizes, int n_in,
                              void* d_out, int out_size, void* d_ws, size_t ws_size,
                              hipStream_t stream) {
    const void* X  = d_in[0];
    const int*  A  = (const int*)d_in[1];
    const void* W  = d_in[2];
    const void* bb = d_in[3];
    const void* as_ = d_in[4];
    const void* ar_ = d_in[5];

    char* ws = (char*)d_ws;
    const size_t OFF_FLAG = 0;
    const size_t OFF_XB   = 256;
    const size_t OFF_WB   = OFF_XB + (size_t)NN * 256 * 2;
    const size_t OFF_BF   = OFF_WB + (size_t)256 * 256 * 2;
    const size_t OFF_ASF  = OFF_BF + 1024;
    const size_t OFF_ARF  = OFF_ASF + 1024;
    const size_t OFF_S    = OFF_ARF + 1024;
    const size_t OFF_R    = OFF_S + (size_t)NN * 4;
    const size_t OFF_GT   = OFF_R + (size_t)NN * 4;
    const size_t OFF_ACC  = OFF_GT + (size_t)64 * NN * 2;
    const size_t OFF_DEN  = OFF_ACC + (size_t)8 * NN * 64 * 4;

    int*   flag = (int*)(ws + OFF_FLAG);
    short* Xb   = (short*)(ws + OFF_XB);
    short* Wb   = (short*)(ws + OFF_WB);
    float* bF   = (float*)(ws + OFF_BF);
    float* asF  = (float*)(ws + OFF_ASF);
    float* arF  = (float*)(ws + OFF_ARF);
    float* sP   = (float*)(ws + OFF_S);
    float* rP   = (float*)(ws + OFF_R);
    short* Gt   = (short*)(ws + OFF_GT);
    float* accP = (float*)(ws + OFF_ACC);
    float* denP = (float*)(ws + OFF_DEN);

    gat_probe_dtype<<<1, 256, 0, stream>>>((const unsigned short*)X, flag);
    gat_convert<<<512, 256, 0, stream>>>(X, W, bb, as_, ar_, Xb, Wb, bF, asF, arF, flag);
    gat_gemm1<<<NN / 32, 128, 0, stream>>>(Xb, Wb, bF, asF, arF, Gt, sP, rP);
    gat_pv4<<<(NN / 32) * 4, 256, 0, stream>>>(A, Gt, sP, rP, accP, denP);
    gat_final<<<NN * 16 / 256, 256, 0, stream>>>(accP, denP, flag, d_out);
}

// Round 5
// 124.563 us; speedup vs baseline: 1.1671x; 1.1671x over previous
//
#include <hip/hip_runtime.h>

typedef __attribute__((ext_vector_type(8))) short short8;
typedef __attribute__((ext_vector_type(4))) short short4v;
typedef __attribute__((ext_vector_type(4))) float f32x4;
typedef __attribute__((ext_vector_type(4))) int i32x4;

#define NN 8192
#define ALPHA 0.2f

__device__ __forceinline__ float bf16_to_f32(unsigned short h) {
    union { unsigned int u; float f; } c;
    c.u = ((unsigned int)h) << 16;
    return c.f;
}
__device__ __forceinline__ unsigned short f32_to_bf16(float f) {
    union { float f; unsigned int u; } c;
    c.f = f;
    unsigned int r = (c.u + 0x7FFFu + ((c.u >> 16) & 1u)) >> 16;
    return (unsigned short)r;
}
// cheaper round-half-up (pv inner loop only; half-ulp bias, cancels in ratio)
__device__ __forceinline__ unsigned short f32_to_bf16_fast(float f) {
    union { float f; unsigned int u; } c;
    c.f = f;
    return (unsigned short)((c.u + 0x8000u) >> 16);
}

// ---------------- kernel 0: probe input dtype -------------------------------
__global__ void gat_probe_dtype(const unsigned short* __restrict__ x16, int* flag) {
    __shared__ int cnts[256];
    int tid = threadIdx.x;
    int cnt = 0;
    for (int i = tid; i < 16384; i += 256) {
        float v = bf16_to_f32(x16[i]);
        float a = fabsf(v);
        if (a > 1e-6f && a < 64.0f) cnt++;   // false for NaN too
    }
    cnts[tid] = cnt;
    __syncthreads();
    for (int s = 128; s > 0; s >>= 1) {
        if (tid < s) cnts[tid] += cnts[tid + s];
        __syncthreads();
    }
    if (tid == 0) *flag = (cnts[0] > 13000) ? 1 : 0;
}

// ---------------- kernel 1: convert inputs to ws copies (vectorized) --------
__global__ void gat_convert(const void* __restrict__ Xv, const void* __restrict__ Wv,
                            const void* __restrict__ bv, const void* __restrict__ asv,
                            const void* __restrict__ arv,
                            short* __restrict__ Xb, short* __restrict__ Wb,
                            float* __restrict__ bF, float* __restrict__ asF,
                            float* __restrict__ arF, const int* __restrict__ flag) {
    const int GX = NN * 256 / 8;      // short8 groups in X
    const int GW = 256 * 256 / 8;     // short8 groups in W
    const int isBf = *flag;
    const int idx = blockIdx.x * blockDim.x + threadIdx.x;
    const int stride = gridDim.x * blockDim.x;
    for (int i = idx; i < GX + GW; i += stride) {
        const void* src = (i < GX) ? Xv : Wv;
        short* dst = (i < GX) ? Xb : Wb;
        int g = (i < GX) ? i : i - GX;
        short8 o;
        if (isBf) {
            o = ((const short8*)src)[g];
        } else {
            f32x4 a = ((const f32x4*)src)[2 * g];
            f32x4 b = ((const f32x4*)src)[2 * g + 1];
#pragma unroll
            for (int j = 0; j < 4; j++) {
                o[j] = (short)f32_to_bf16(a[j]);
                o[4 + j] = (short)f32_to_bf16(b[j]);
            }
        }
        ((short8*)dst)[g] = o;
    }
    if (idx < 768) {
        int which = idx >> 8;
        int k = idx & 255;
        const void* src = (which == 0) ? bv : (which == 1) ? asv : arv;
        float v = isBf ? bf16_to_f32(((const unsigned short*)src)[k])
                       : ((const float*)src)[k];
        float* dst = (which == 0) ? bF : (which == 1) ? asF : arF;
        dst[k] = v;
    }
}

// ---------------- kernel 2: H_in = X*W^T + b -> Gt, s, r ---------------------
__global__ __launch_bounds__(128) void gat_gemm1(
    const short* __restrict__ Xb, const short* __restrict__ Wb,
    const float* __restrict__ bF, const float* __restrict__ asF,
    const float* __restrict__ arF,
    short* __restrict__ Gt, float* __restrict__ sOut, float* __restrict__ rOut) {
    const int tid = threadIdx.x;
    const int wave = tid >> 6, lane = tid & 63;
    const int l15 = lane & 15, lhi = lane >> 4;
    const int rowBase = blockIdx.x * 32 + wave * 16;

    f32x4 acc[16];
#pragma unroll
    for (int n = 0; n < 16; n++) acc[n] = (f32x4){0.f, 0.f, 0.f, 0.f};

    const short8* Xrow = (const short8*)(Xb + (size_t)(rowBase + l15) * 256);
#pragma unroll
    for (int ks = 0; ks < 8; ks++) {            // K = 256 in steps of 32
        short8 a = Xrow[ks * 4 + lhi];
#pragma unroll
        for (int n = 0; n < 16; n++) {
            const short8* Wrow = (const short8*)(Wb + (size_t)(n * 16 + l15) * 256);
            short8 bf = Wrow[ks * 4 + lhi];
            acc[n] = __builtin_amdgcn_mfma_f32_16x16x32_bf16(a, bf, acc[n], 0, 0, 0);
        }
    }

    float sPart[4] = {0.f, 0.f, 0.f, 0.f};
    float rPart[4] = {0.f, 0.f, 0.f, 0.f};
    float g[4][4];
#pragma unroll
    for (int na = 0; na < 4; na++)
#pragma unroll
        for (int q = 0; q < 4; q++) g[na][q] = 0.f;

#pragma unroll
    for (int n = 0; n < 16; n++) {
        int col = n * 16 + l15;
        float bias = bF[col], asc = asF[col], arc = arF[col];
#pragma unroll
        for (int q = 0; q < 4; q++) {
            float h = acc[n][q] + bias;         // D: row=lhi*4+q, col=l15
            sPart[q] += h * asc;
            rPart[q] += h * arc;
            g[n & 3][q] += h;                   // head-sum
        }
    }
#pragma unroll
    for (int na = 0; na < 4; na++) {
        short4v pk;
#pragma unroll
        for (int q = 0; q < 4; q++) pk[q] = (short)f32_to_bf16(g[na][q]);
        *(short4v*)(Gt + (size_t)(na * 16 + l15) * NN + rowBase + lhi * 4) = pk;
    }

#pragma unroll
    for (int m = 1; m <= 8; m <<= 1) {
#pragma unroll
        for (int q = 0; q < 4; q++) {
            sPart[q] += __shfl_xor(sPart[q], m, 64);
            rPart[q] += __shfl_xor(rPart[q], m, 64);
        }
    }
    if (l15 == 0) {
#pragma unroll
        for (int q = 0; q < 4; q++) {
            int row = rowBase + lhi * 4 + q;
            sOut[row] = sPart[q];
            rOut[row] = rPart[q];
        }
    }
}

// ---------------- kernel 3: fused masked-softmax PV (v5) --------------------
// COALESCED A loads (4 rows x 256B runs, nontemporal, double-buffered) +
// BALLOT-based mask transpose: the only cross-lane data is the 0/1 mask,
// moved as 16 wave-uniform 64-bit ballot words per 16x64 tile. P (exp) is
// computed directly by the MFMA-fragment owner lane; no LDS, no atomics.
// Ballot word W[r][j] bit l = (A[rowTop+(l>>4)*4+r][k0+(l&15)*4+j] != 0).
// Fragment lane (l15,lhi), k=k0+KS*32+lhi*8+j': word (r=l15&3, j=j'&3),
// bit = 16*(l15>>2) + KS*8 + lhi*2 + (j'>>2)  ->  shBase + {0,1,8,9}.

#define GAT_LOADA(D0, D1, D2, D3, T_)                                        \
    {                                                                        \
        const int* p_ = ab + (size_t)(ksBase + (T_)) * 64;                   \
        D0 = __builtin_nontemporal_load((const i32x4*)(p_));                 \
        D1 = __builtin_nontemporal_load((const i32x4*)(p_ + NN));            \
        D2 = __builtin_nontemporal_load((const i32x4*)(p_ + 2 * NN));        \
        D3 = __builtin_nontemporal_load((const i32x4*)(p_ + 3 * NN));        \
    }

#define GAT_ELEM(PA_, JP_, RVAL_, TW_, SH_)                                  \
    {                                                                        \
        float x_ = sMine + (RVAL_);                                          \
        x_ = fmaxf(x_, ALPHA * x_);                                          \
        float e_ = __expf(x_);                                               \
        PA_[JP_] = ((TW_ >> (SH_)) & 1u) ? (short)f32_to_bf16_fast(e_)       \
                                         : (short)0;                         \
    }

#define GAT_BODY(T_, AV0, AV1, AV2, AV3)                                     \
    {                                                                        \
        const int k0_ = (ksBase + (T_)) * 64;                                \
        f32x4 ra0 = *(const f32x4*)(rvb + k0_);                              \
        f32x4 ra1 = *(const f32x4*)(rvb + k0_ + 4);                          \
        f32x4 rb0 = *(const f32x4*)(rvb + k0_ + 32);                         \
        f32x4 rb1 = *(const f32x4*)(rvb + k0_ + 36);                         \
        unsigned long long W00 = __ballot(AV0[0] != 0);                      \
        unsigned long long W01 = __ballot(AV0[1] != 0);                      \
        unsigned long long W02 = __ballot(AV0[2] != 0);                      \
        unsigned long long W03 = __ballot(AV0[3] != 0);                      \
        unsigned long long W10 = __ballot(AV1[0] != 0);                      \
        unsigned long long W11 = __ballot(AV1[1] != 0);                      \
        unsigned long long W12 = __ballot(AV1[2] != 0);                      \
        unsigned long long W13 = __ballot(AV1[3] != 0);                      \
        unsigned long long W20 = __ballot(AV2[0] != 0);                      \
        unsigned long long W21 = __ballot(AV2[1] != 0);                      \
        unsigned long long W22 = __ballot(AV2[2] != 0);                      \
        unsigned long long W23 = __ballot(AV2[3] != 0);                      \
        unsigned long long W30 = __ballot(AV3[0] != 0);                      \
        unsigned long long W31 = __ballot(AV3[1] != 0);                      \
        unsigned long long W32 = __ballot(AV3[2] != 0);                      \
        unsigned long long W33 = __ballot(AV3[3] != 0);                      \
        unsigned long long w0 = r3 == 0 ? W00 : r3 == 1 ? W10                \
                              : r3 == 2 ? W20 : W30;                         \
        unsigned long long w1 = r3 == 0 ? W01 : r3 == 1 ? W11                \
                              : r3 == 2 ? W21 : W31;                         \
        unsigned long long w2 = r3 == 0 ? W02 : r3 == 1 ? W12                \
                              : r3 == 2 ? W22 : W32;                         \
        unsigned long long w3 = r3 == 0 ? W03 : r3 == 1 ? W13                \
                              : r3 == 2 ? W23 : W33;                         \
        unsigned int t0 = (unsigned int)(w0 >> shBase);                      \
        unsigned int t1 = (unsigned int)(w1 >> shBase);                      \
        unsigned int t2 = (unsigned int)(w2 >> shBase);                      \
        unsigned int t3 = (unsigned int)(w3 >> shBase);                      \
        {   /* half 0: k = k0_ + lhi*8 + j' */                               \
            short8 pa;                                                       \
            GAT_ELEM(pa, 0, ra0[0], t0, 0) GAT_ELEM(pa, 1, ra0[1], t1, 0)    \
            GAT_ELEM(pa, 2, ra0[2], t2, 0) GAT_ELEM(pa, 3, ra0[3], t3, 0)    \
            GAT_ELEM(pa, 4, ra1[0], t0, 1) GAT_ELEM(pa, 5, ra1[1], t1, 1)    \
            GAT_ELEM(pa, 6, ra1[2], t2, 1) GAT_ELEM(pa, 7, ra1[3], t3, 1)    \
            _Pragma("unroll") for (int n = 0; n < 4; n++) {                  \
                short8 bfr = *(const short8*)(gbase + (size_t)n * 16 * NN +  \
                                              k0_);                          \
                acc[n] = __builtin_amdgcn_mfma_f32_16x16x32_bf16(            \
                    pa, bfr, acc[n], 0, 0, 0);                               \
            }                                                                \
            acc[4] = __builtin_amdgcn_mfma_f32_16x16x32_bf16(                \
                pa, onesB, acc[4], 0, 0, 0);                                 \
        }                                                                    \
        {   /* half 1: k = k0_ + 32 + lhi*8 + j' */                          \
            short8 pa;                                                       \
            GAT_ELEM(pa, 0, rb0[0], t0, 8) GAT_ELEM(pa, 1, rb0[1], t1, 8)    \
            GAT_ELEM(pa, 2, rb0[2], t2, 8) GAT_ELEM(pa, 3, rb0[3], t3, 8)    \
            GAT_ELEM(pa, 4, rb1[0], t0, 9) GAT_ELEM(pa, 5, rb1[1], t1, 9)    \
            GAT_ELEM(pa, 6, rb1[2], t2, 9) GAT_ELEM(pa, 7, rb1[3], t3, 9)    \
            _Pragma("unroll") for (int n = 0; n < 4; n++) {                  \
                short8 bfr = *(const short8*)(gbase + (size_t)n * 16 * NN +  \
                                              k0_ + 32);                     \
                acc[n] = __builtin_amdgcn_mfma_f32_16x16x32_bf16(            \
                    pa, bfr, acc[n], 0, 0, 0);                               \
            }                                                                \
            acc[4] = __builtin_amdgcn_mfma_f32_16x16x32_bf16(                \
                pa, onesB, acc[4], 0, 0, 0);                                 \
        }                                                                    \
    }

__global__ __launch_bounds__(256, 4) void gat_pv5(
    const int* __restrict__ A, const short* __restrict__ Gt,
    const float* __restrict__ sV, const float* __restrict__ rV,
    float* __restrict__ accP, float* __restrict__ denP) {
    const int tid = threadIdx.x;
    const int wave = tid >> 6, lane = tid & 63;
    const int l15 = lane & 15, lhi = lane >> 4;
    const int rgroup = lane >> 4, kq = lane & 15;   // A-load mapping
    const int wm = wave >> 1, wk = wave & 1;
    const int rb = blockIdx.x >> 2;
    const int ks = blockIdx.x & 3;
    const int i0 = rb * 32;
    const int sk = ks * 2 + wk;
    const int rowTop = i0 + wm * 16;
    const int ksBase = ks * 32 + wk * 16;       // first 64-k tile index

    const int r3 = l15 & 3;
    const int shBase = ((l15 >> 2) << 4) + (lhi << 1);

    const float sMine = sV[rowTop + l15];
    const int* ab = A + (size_t)(rowTop + rgroup * 4) * NN + kq * 4;
    const float* rvb = rV + lhi * 8;
    const short* gbase = Gt + (size_t)l15 * NN + lhi * 8;

    short8 onesB;
#pragma unroll
    for (int j = 0; j < 8; j++) onesB[j] = (l15 == 0) ? (short)0x3F80 : (short)0;

    f32x4 acc[5];
#pragma unroll
    for (int n = 0; n < 5; n++) acc[n] = (f32x4){0.f, 0.f, 0.f, 0.f};

    i32x4 a0, a1, a2, a3, b0, b1, b2, b3;
    GAT_LOADA(a0, a1, a2, a3, 0);
    for (int t = 0; t < 16; t += 2) {
        GAT_LOADA(b0, b1, b2, b3, t + 1);
        GAT_BODY(t, a0, a1, a2, a3);
        {
            const int t2 = (t + 2 < 16) ? t + 2 : 15;  // tail: redundant reload
            GAT_LOADA(a0, a1, a2, a3, t2);
        }
        GAT_BODY(t + 1, b0, b1, b2, b3);
    }

    // partial accumulator store (disjoint per slice, coalesced 64B/quarter)
    float* aout = accP + (size_t)sk * NN * 64;
#pragma unroll
    for (int n = 0; n < 4; n++)
#pragma unroll
        for (int q = 0; q < 4; q++)
            aout[(size_t)(rowTop + lhi * 4 + q) * 64 + n * 16 + l15] = acc[n][q];

    // denominators from the ones-column MFMA: col 0 lives in lanes l15==0
    if (l15 == 0) {
#pragma unroll
        for (int q = 0; q < 4; q++)
            denP[(size_t)sk * NN + rowTop + lhi * 4 + q] = acc[4][q];
    }
}

// ---------------- kernel 4: sum 8 partials, divide, cast --------------------
__global__ void gat_final(const float* __restrict__ accP, const float* __restrict__ denP,
                          const int* __restrict__ flag, void* __restrict__ outP) {
    int idx = blockIdx.x * blockDim.x + threadIdx.x;  // one f32x4 group
    if (idx >= NN * 16) return;
    int row = idx >> 4;
    float den = 0.f;
    f32x4 v = (f32x4){0.f, 0.f, 0.f, 0.f};
#pragma unroll
    for (int sk = 0; sk < 8; sk++) {
        den += denP[(size_t)sk * NN + row];
        f32x4 a = *((const f32x4*)(accP + (size_t)sk * NN * 64) + idx);
        v.x += a.x; v.y += a.y; v.z += a.z; v.w += a.w;
    }
    float inv = 1.0f / den;
    v.x *= inv; v.y *= inv; v.z *= inv; v.w *= inv;
    if (*flag) {
        short4v pk;
#pragma unroll
        for (int j = 0; j < 4; j++) pk[j] = (short)f32_to_bf16(v[j]);
        *((short4v*)outP + idx) = pk;
    } else {
        *((f32x4*)outP + idx) = v;
    }
}

// ---------------- launch -----------------------------------------------------
extern "C" void kernel_launch(void* const* d_in, const int* in_sizes, int n_in,
                              void* d_out, int out_size, void* d_ws, size_t ws_size,
                              hipStream_t stream) {
    const void* X  = d_in[0];
    const int*  A  = (const int*)d_in[1];
    const void* W  = d_in[2];
    const void* bb = d_in[3];
    const void* as_ = d_in[4];
    const void* ar_ = d_in[5];

    char* ws = (char*)d_ws;
    const size_t OFF_FLAG = 0;
    const size_t OFF_XB   = 256;
    const size_t OFF_WB   = OFF_XB + (size_t)NN * 256 * 2;
    const size_t OFF_BF   = OFF_WB + (size_t)256 * 256 * 2;
    const size_t OFF_ASF  = OFF_BF + 1024;
    const size_t OFF_ARF  = OFF_ASF + 1024;
    const size_t OFF_S    = OFF_ARF + 1024;
    const size_t OFF_R    = OFF_S + (size_t)NN * 4;
    const size_t OFF_GT   = OFF_R + (size_t)NN * 4;
    const size_t OFF_ACC  = OFF_GT + (size_t)64 * NN * 2;
    const size_t OFF_DEN  = OFF_ACC + (size_t)8 * NN * 64 * 4;

    int*   flag = (int*)(ws + OFF_FLAG);
    short* Xb   = (short*)(ws + OFF_XB);
    short* Wb   = (short*)(ws + OFF_WB);
    float* bF   = (float*)(ws + OFF_BF);
    float* asF  = (float*)(ws + OFF_ASF);
    float* arF  = (float*)(ws + OFF_ARF);
    float* sP   = (float*)(ws + OFF_S);
    float* rP   = (float*)(ws + OFF_R);
    short* Gt   = (short*)(ws + OFF_GT);
    float* accP = (float*)(ws + OFF_ACC);
    float* denP = (float*)(ws + OFF_DEN);

    gat_probe_dtype<<<1, 256, 0, stream>>>((const unsigned short*)X, flag);
    gat_convert<<<512, 256, 0, stream>>>(X, W, bb, as_, ar_, Xb, Wb, bF, asF, arF, flag);
    gat_gemm1<<<NN / 32, 128, 0, stream>>>(Xb, Wb, bF, asF, arF, Gt, sP, rP);
    gat_pv5<<<(NN / 32) * 4, 256, 0, stream>>>(A, Gt, sP, rP, accP, denP);
    gat_final<<<NN * 16 / 256, 256, 0, stream>>>(accP, denP, flag, d_out);
}

// Round 6
// 95.944 us; speedup vs baseline: 1.5153x; 1.2983x over previous
//
#include <hip/hip_runtime.h>

typedef __attribute__((ext_vector_type(8))) short short8;
typedef __attribute__((ext_vector_type(4))) short short4v;
typedef __attribute__((ext_vector_type(4))) float f32x4;
typedef __attribute__((ext_vector_type(4))) int i32x4;

#define NN 8192
#define ALPHA 0.2f

__device__ __forceinline__ float bf16_to_f32(unsigned short h) {
    union { unsigned int u; float f; } c;
    c.u = ((unsigned int)h) << 16;
    return c.f;
}
__device__ __forceinline__ unsigned short f32_to_bf16(float f) {
    union { float f; unsigned int u; } c;
    c.f = f;
    unsigned int r = (c.u + 0x7FFFu + ((c.u >> 16) & 1u)) >> 16;
    return (unsigned short)r;
}
// cheaper round-half-up (pv inner loop only; half-ulp bias, cancels in ratio)
__device__ __forceinline__ unsigned short f32_to_bf16_fast(float f) {
    union { float f; unsigned int u; } c;
    c.f = f;
    return (unsigned short)((c.u + 0x8000u) >> 16);
}

// ---------------- kernel 0: probe input dtype -------------------------------
__global__ void gat_probe_dtype(const unsigned short* __restrict__ x16, int* flag) {
    __shared__ int cnts[256];
    int tid = threadIdx.x;
    int cnt = 0;
    for (int i = tid; i < 16384; i += 256) {
        float v = bf16_to_f32(x16[i]);
        float a = fabsf(v);
        if (a > 1e-6f && a < 64.0f) cnt++;   // false for NaN too
    }
    cnts[tid] = cnt;
    __syncthreads();
    for (int s = 128; s > 0; s >>= 1) {
        if (tid < s) cnts[tid] += cnts[tid + s];
        __syncthreads();
    }
    if (tid == 0) *flag = (cnts[0] > 13000) ? 1 : 0;
}

// ---------------- kernel 1: convert inputs to ws copies (vectorized) --------
__global__ void gat_convert(const void* __restrict__ Xv, const void* __restrict__ Wv,
                            const void* __restrict__ bv, const void* __restrict__ asv,
                            const void* __restrict__ arv,
                            short* __restrict__ Xb, short* __restrict__ Wb,
                            float* __restrict__ bF, float* __restrict__ asF,
                            float* __restrict__ arF, const int* __restrict__ flag) {
    const int GX = NN * 256 / 8;      // short8 groups in X
    const int GW = 256 * 256 / 8;     // short8 groups in W
    const int isBf = *flag;
    const int idx = blockIdx.x * blockDim.x + threadIdx.x;
    const int stride = gridDim.x * blockDim.x;
    for (int i = idx; i < GX + GW; i += stride) {
        const void* src = (i < GX) ? Xv : Wv;
        short* dst = (i < GX) ? Xb : Wb;
        int g = (i < GX) ? i : i - GX;
        short8 o;
        if (isBf) {
            o = ((const short8*)src)[g];
        } else {
            f32x4 a = ((const f32x4*)src)[2 * g];
            f32x4 b = ((const f32x4*)src)[2 * g + 1];
#pragma unroll
            for (int j = 0; j < 4; j++) {
                o[j] = (short)f32_to_bf16(a[j]);
                o[4 + j] = (short)f32_to_bf16(b[j]);
            }
        }
        ((short8*)dst)[g] = o;
    }
    if (idx < 768) {
        int which = idx >> 8;
        int k = idx & 255;
        const void* src = (which == 0) ? bv : (which == 1) ? asv : arv;
        float v = isBf ? bf16_to_f32(((const unsigned short*)src)[k])
                       : ((const float*)src)[k];
        float* dst = (which == 0) ? bF : (which == 1) ? asF : arF;
        dst[k] = v;
    }
}

// ---------------- kernel 2: H_in = X*W^T + b -> Gfrag, s, r ------------------
// As before, but the head-summed G is emitted in MFMA-B-FRAGMENT-MAJOR order:
// Gfrag[fid][lane][j] with fid = ktile*8 + half*4 + n, so the PV kernel's
// B-loads are fully coalesced (1KB contiguous per instruction).
// value(fid,lane,j) = G[col = n*16 + (lane&15)][k = ktile*64 + half*32 +
//                       (lane>>4)*8 + j]   (k = node-row index)
__global__ __launch_bounds__(128) void gat_gemm1(
    const short* __restrict__ Xb, const short* __restrict__ Wb,
    const float* __restrict__ bF, const float* __restrict__ asF,
    const float* __restrict__ arF,
    short* __restrict__ Gfrag, float* __restrict__ sOut, float* __restrict__ rOut) {
    __shared__ short Gl[64][32];      // [col][local node-row]
    const int tid = threadIdx.x;
    const int wave = tid >> 6, lane = tid & 63;
    const int l15 = lane & 15, lhi = lane >> 4;
    const int rowBase = blockIdx.x * 32 + wave * 16;

    f32x4 acc[16];
#pragma unroll
    for (int n = 0; n < 16; n++) acc[n] = (f32x4){0.f, 0.f, 0.f, 0.f};

    const short8* Xrow = (const short8*)(Xb + (size_t)(rowBase + l15) * 256);
#pragma unroll
    for (int ks = 0; ks < 8; ks++) {            // K = 256 in steps of 32
        short8 a = Xrow[ks * 4 + lhi];
#pragma unroll
        for (int n = 0; n < 16; n++) {
            const short8* Wrow = (const short8*)(Wb + (size_t)(n * 16 + l15) * 256);
            short8 bf = Wrow[ks * 4 + lhi];
            acc[n] = __builtin_amdgcn_mfma_f32_16x16x32_bf16(a, bf, acc[n], 0, 0, 0);
        }
    }

    float sPart[4] = {0.f, 0.f, 0.f, 0.f};
    float rPart[4] = {0.f, 0.f, 0.f, 0.f};
    float g[4][4];
#pragma unroll
    for (int na = 0; na < 4; na++)
#pragma unroll
        for (int q = 0; q < 4; q++) g[na][q] = 0.f;

#pragma unroll
    for (int n = 0; n < 16; n++) {
        int col = n * 16 + l15;
        float bias = bF[col], asc = asF[col], arc = arF[col];
#pragma unroll
        for (int q = 0; q < 4; q++) {
            float h = acc[n][q] + bias;         // D: row=lhi*4+q, col=l15
            sPart[q] += h * asc;
            rPart[q] += h * arc;
            g[n & 3][q] += h;                   // head-sum
        }
    }

    // stage G tile in LDS: Gl[col][klocal], klocal = wave*16 + lhi*4 + q
#pragma unroll
    for (int na = 0; na < 4; na++)
#pragma unroll
        for (int q = 0; q < 4; q++)
            Gl[na * 16 + l15][wave * 16 + lhi * 4 + q] = (short)f32_to_bf16(g[na][q]);

#pragma unroll
    for (int m = 1; m <= 8; m <<= 1) {
#pragma unroll
        for (int q = 0; q < 4; q++) {
            sPart[q] += __shfl_xor(sPart[q], m, 64);
            rPart[q] += __shfl_xor(rPart[q], m, 64);
        }
    }
    if (l15 == 0) {
#pragma unroll
        for (int q = 0; q < 4; q++) {
            int row = rowBase + lhi * 4 + q;
            sOut[row] = sPart[q];
            rOut[row] = rPart[q];
        }
    }

    __syncthreads();
    // pack fragment-major: this block covers ktile t_ = bid>>1, half h_ = bid&1
    const int t_ = blockIdx.x >> 1, h_ = blockIdx.x & 1;
#pragma unroll
    for (int e = tid; e < 256; e += 128) {
        int n_ = e >> 6, le = e & 63;
        short8 v = *(const short8*)(&Gl[n_ * 16 + (le & 15)][(le >> 4) * 8]);
        *(short8*)(Gfrag + ((size_t)t_ * 8 + h_ * 4 + n_) * 512 + le * 8) = v;
    }
}

// ---------------- kernel 3: fused masked-softmax PV (v6) --------------------
// Grid = 256 row-blocks x 4 k-slices, 256 thr. Block: rows i0..i0+31, k-slice
// ks*2048. Wave wk owns 8 contiguous 64-k tiles; EACH WAVE COVERS ALL 32 ROWS
// (2 row-groups) so the coalesced Gfrag B-loads amortize over 2x rows.
// A loads coalesced + ballot mask-transpose (pv5 scheme, per row-group).
// End: 4 waves combine partials in LDS, one store per block to accP[ks].

#define GAT_LOADA(S0, S1, S2, S3, AB_, T_)                                   \
    {                                                                        \
        const int* p_ = (AB_) + (size_t)(T_) * 64;                           \
        S0 = __builtin_nontemporal_load((const i32x4*)(p_));                 \
        S1 = __builtin_nontemporal_load((const i32x4*)(p_ + NN));            \
        S2 = __builtin_nontemporal_load((const i32x4*)(p_ + 2 * NN));        \
        S3 = __builtin_nontemporal_load((const i32x4*)(p_ + 3 * NN));        \
    }

#define GAT_BAL(Q0, Q1, Q2, Q3, V0, V1, V2, V3)                              \
    {                                                                        \
        unsigned long long W00 = __ballot((V0)[0] != 0);                     \
        unsigned long long W01 = __ballot((V0)[1] != 0);                     \
        unsigned long long W02 = __ballot((V0)[2] != 0);                     \
        unsigned long long W03 = __ballot((V0)[3] != 0);                     \
        unsigned long long W10 = __ballot((V1)[0] != 0);                     \
        unsigned long long W11 = __ballot((V1)[1] != 0);                     \
        unsigned long long W12 = __ballot((V1)[2] != 0);                     \
        unsigned long long W13 = __ballot((V1)[3] != 0);                     \
        unsigned long long W20 = __ballot((V2)[0] != 0);                     \
        unsigned long long W21 = __ballot((V2)[1] != 0);                     \
        unsigned long long W22 = __ballot((V2)[2] != 0);                     \
        unsigned long long W23 = __ballot((V2)[3] != 0);                     \
        unsigned long long W30 = __ballot((V3)[0] != 0);                     \
        unsigned long long W31 = __ballot((V3)[1] != 0);                     \
        unsigned long long W32 = __ballot((V3)[2] != 0);                     \
        unsigned long long W33 = __ballot((V3)[3] != 0);                     \
        unsigned long long w0_ = r3 == 0 ? W00 : r3 == 1 ? W10               \
                               : r3 == 2 ? W20 : W30;                        \
        unsigned long long w1_ = r3 == 0 ? W01 : r3 == 1 ? W11               \
                               : r3 == 2 ? W21 : W31;                        \
        unsigned long long w2_ = r3 == 0 ? W02 : r3 == 1 ? W12               \
                               : r3 == 2 ? W22 : W32;                        \
        unsigned long long w3_ = r3 == 0 ? W03 : r3 == 1 ? W13               \
                               : r3 == 2 ? W23 : W33;                        \
        Q0 = (unsigned int)(w0_ >> shBase);                                  \
        Q1 = (unsigned int)(w1_ >> shBase);                                  \
        Q2 = (unsigned int)(w2_ >> shBase);                                  \
        Q3 = (unsigned int)(w3_ >> shBase);                                  \
    }

#define GAT_ELEM(PA_, JP_, XV_, TW_, SH_)                                    \
    {                                                                        \
        float x_ = (XV_);                                                    \
        x_ = fmaxf(x_, ALPHA * x_);                                          \
        float e_ = __expf(x_);                                               \
        PA_[JP_] = ((TW_ >> (SH_)) & 1u) ? (short)f32_to_bf16_fast(e_)       \
                                         : (short)0;                         \
    }

#define GAT_PA(PAH0, PAH1, SM_, Q0, Q1, Q2, Q3)                              \
    {                                                                        \
        GAT_ELEM(PAH0, 0, (SM_) + ra0[0], Q0, 0)                             \
        GAT_ELEM(PAH0, 1, (SM_) + ra0[1], Q1, 0)                             \
        GAT_ELEM(PAH0, 2, (SM_) + ra0[2], Q2, 0)                             \
        GAT_ELEM(PAH0, 3, (SM_) + ra0[3], Q3, 0)                             \
        GAT_ELEM(PAH0, 4, (SM_) + ra1[0], Q0, 1)                             \
        GAT_ELEM(PAH0, 5, (SM_) + ra1[1], Q1, 1)                             \
        GAT_ELEM(PAH0, 6, (SM_) + ra1[2], Q2, 1)                             \
        GAT_ELEM(PAH0, 7, (SM_) + ra1[3], Q3, 1)                             \
        GAT_ELEM(PAH1, 0, (SM_) + rb0[0], Q0, 8)                             \
        GAT_ELEM(PAH1, 1, (SM_) + rb0[1], Q1, 8)                             \
        GAT_ELEM(PAH1, 2, (SM_) + rb0[2], Q2, 8)                             \
        GAT_ELEM(PAH1, 3, (SM_) + rb0[3], Q3, 8)                             \
        GAT_ELEM(PAH1, 4, (SM_) + rb1[0], Q0, 9)                             \
        GAT_ELEM(PAH1, 5, (SM_) + rb1[1], Q1, 9)                             \
        GAT_ELEM(PAH1, 6, (SM_) + rb1[2], Q2, 9)                             \
        GAT_ELEM(PAH1, 7, (SM_) + rb1[3], Q3, 9)                             \
    }

#define GAT_MFMA_HALF(H_)                                                    \
    {                                                                        \
        const short* bp_ = Gfrag + ((size_t)ktg * 8 + (H_) * 4) * 512 +      \
                           lane * 8;                                         \
        short8 bv0 = *(const short8*)(bp_);                                  \
        short8 bv1 = *(const short8*)(bp_ + 512);                            \
        short8 bv2 = *(const short8*)(bp_ + 1024);                           \
        short8 bv3 = *(const short8*)(bp_ + 1536);                           \
        acc[0][0] = __builtin_amdgcn_mfma_f32_16x16x32_bf16(pa0[H_], bv0,    \
                                                            acc[0][0], 0, 0, 0); \
        acc[0][1] = __builtin_amdgcn_mfma_f32_16x16x32_bf16(pa0[H_], bv1,    \
                                                            acc[0][1], 0, 0, 0); \
        acc[0][2] = __builtin_amdgcn_mfma_f32_16x16x32_bf16(pa0[H_], bv2,    \
                                                            acc[0][2], 0, 0, 0); \
        acc[0][3] = __builtin_amdgcn_mfma_f32_16x16x32_bf16(pa0[H_], bv3,    \
                                                            acc[0][3], 0, 0, 0); \
        acc[0][4] = __builtin_amdgcn_mfma_f32_16x16x32_bf16(pa0[H_], onesB,  \
                                                            acc[0][4], 0, 0, 0); \
        acc[1][0] = __builtin_amdgcn_mfma_f32_16x16x32_bf16(pa1[H_], bv0,    \
                                                            acc[1][0], 0, 0, 0); \
        acc[1][1] = __builtin_amdgcn_mfma_f32_16x16x32_bf16(pa1[H_], bv1,    \
                                                            acc[1][1], 0, 0, 0); \
        acc[1][2] = __builtin_amdgcn_mfma_f32_16x16x32_bf16(pa1[H_], bv2,    \
                                                            acc[1][2], 0, 0, 0); \
        acc[1][3] = __builtin_amdgcn_mfma_f32_16x16x32_bf16(pa1[H_], bv3,    \
                                                            acc[1][3], 0, 0, 0); \
        acc[1][4] = __builtin_amdgcn_mfma_f32_16x16x32_bf16(pa1[H_], onesB,  \
                                                            acc[1][4], 0, 0, 0); \
    }

__global__ __launch_bounds__(256, 3) void gat_pv6(
    const int* __restrict__ A, const short* __restrict__ Gfrag,
    const float* __restrict__ sV, const float* __restrict__ rV,
    float* __restrict__ accP, float* __restrict__ denP) {
    __shared__ float Ls[4][32][68];   // pad 68: break 8-way bank conflict
    __shared__ float Ld[4][32];

    const int tid = threadIdx.x;
    const int wave = tid >> 6, lane = tid & 63;
    const int l15 = lane & 15, lhi = lane >> 4;
    const int rb = blockIdx.x >> 2;
    const int ks = blockIdx.x & 3;
    const int i0 = rb * 32;
    const int ksBase = ks * 32 + wave * 8;      // first 64-k tile (global idx)

    const int r3 = l15 & 3;
    const int shBase = ((l15 >> 2) << 4) + (lhi << 1);

    const float s0m = sV[i0 + l15];
    const float s1m = sV[i0 + 16 + l15];
    const int* ab0 = A + (size_t)(i0 + lhi * 4) * NN + l15 * 4;
    const int* ab1 = ab0 + (size_t)16 * NN;
    const float* rvb = rV + lhi * 8;

    short8 onesB;
#pragma unroll
    for (int j = 0; j < 8; j++) onesB[j] = (l15 == 0) ? (short)0x3F80 : (short)0;

    f32x4 acc[2][5];
#pragma unroll
    for (int rg = 0; rg < 2; rg++)
#pragma unroll
        for (int n = 0; n < 5; n++) acc[rg][n] = (f32x4){0.f, 0.f, 0.f, 0.f};

    i32x4 s00, s01, s02, s03, s10, s11, s12, s13;
    GAT_LOADA(s00, s01, s02, s03, ab0, ksBase);
    GAT_LOADA(s10, s11, s12, s13, ab1, ksBase);

    for (int t = 0; t < 8; t++) {
        const int ktg = ksBase + t;
        const int k0 = ktg * 64;
        f32x4 ra0 = *(const f32x4*)(rvb + k0);
        f32x4 ra1 = *(const f32x4*)(rvb + k0 + 4);
        f32x4 rb0 = *(const f32x4*)(rvb + k0 + 32);
        f32x4 rb1 = *(const f32x4*)(rvb + k0 + 36);

        unsigned int q00, q01, q02, q03, q10, q11, q12, q13;
        GAT_BAL(q00, q01, q02, q03, s00, s01, s02, s03);
        GAT_BAL(q10, q11, q12, q13, s10, s11, s12, s13);

        const int tn = (t < 7) ? ktg + 1 : ktg;   // tail: redundant reload
        GAT_LOADA(s00, s01, s02, s03, ab0, tn);
        GAT_LOADA(s10, s11, s12, s13, ab1, tn);

        short8 pa0[2], pa1[2];
        GAT_PA(pa0[0], pa0[1], s0m, q00, q01, q02, q03);
        GAT_PA(pa1[0], pa1[1], s1m, q10, q11, q12, q13);

        GAT_MFMA_HALF(0);
        GAT_MFMA_HALF(1);
    }

    // combine the 4 waves' partials in LDS (single barrier, no atomics)
#pragma unroll
    for (int rg = 0; rg < 2; rg++)
#pragma unroll
        for (int n = 0; n < 4; n++)
#pragma unroll
            for (int q = 0; q < 4; q++)
                Ls[wave][rg * 16 + lhi * 4 + q][n * 16 + l15] = acc[rg][n][q];
    if (l15 == 0) {
#pragma unroll
        for (int rg = 0; rg < 2; rg++)
#pragma unroll
            for (int q = 0; q < 4; q++)
                Ld[wave][rg * 16 + lhi * 4 + q] = acc[rg][4][q];
    }
    __syncthreads();

    const int row = tid >> 3, c0 = (tid & 7) * 8;
    float v[8];
#pragma unroll
    for (int j = 0; j < 8; j++)
        v[j] = Ls[0][row][c0 + j] + Ls[1][row][c0 + j] +
               Ls[2][row][c0 + j] + Ls[3][row][c0 + j];
    float* aout = accP + (size_t)ks * NN * 64 + (size_t)(i0 + row) * 64 + c0;
    *(f32x4*)aout = (f32x4){v[0], v[1], v[2], v[3]};
    *((f32x4*)aout + 1) = (f32x4){v[4], v[5], v[6], v[7]};
    if (tid < 32)
        denP[(size_t)ks * NN + i0 + tid] =
            Ld[0][tid] + Ld[1][tid] + Ld[2][tid] + Ld[3][tid];
}

// ---------------- kernel 4: sum 4 partials, divide, cast --------------------
__global__ void gat_final(const float* __restrict__ accP, const float* __restrict__ denP,
                          const int* __restrict__ flag, void* __restrict__ outP) {
    int idx = blockIdx.x * blockDim.x + threadIdx.x;  // one f32x4 group
    if (idx >= NN * 16) return;
    int row = idx >> 4;
    float den = 0.f;
    f32x4 v = (f32x4){0.f, 0.f, 0.f, 0.f};
#pragma unroll
    for (int sk = 0; sk < 4; sk++) {
        den += denP[(size_t)sk * NN + row];
        f32x4 a = *((const f32x4*)(accP + (size_t)sk * NN * 64) + idx);
        v.x += a.x; v.y += a.y; v.z += a.z; v.w += a.w;
    }
    float inv = 1.0f / den;
    v.x *= inv; v.y *= inv; v.z *= inv; v.w *= inv;
    if (*flag) {
        short4v pk;
#pragma unroll
        for (int j = 0; j < 4; j++) pk[j] = (short)f32_to_bf16(v[j]);
        *((short4v*)outP + idx) = pk;
    } else {
        *((f32x4*)outP + idx) = v;
    }
}

// ---------------- launch -----------------------------------------------------
extern "C" void kernel_launch(void* const* d_in, const int* in_sizes, int n_in,
                              void* d_out, int out_size, void* d_ws, size_t ws_size,
                              hipStream_t stream) {
    const void* X  = d_in[0];
    const int*  A  = (const int*)d_in[1];
    const void* W  = d_in[2];
    const void* bb = d_in[3];
    const void* as_ = d_in[4];
    const void* ar_ = d_in[5];

    char* ws = (char*)d_ws;
    const size_t OFF_FLAG = 0;
    const size_t OFF_XB   = 256;
    const size_t OFF_WB   = OFF_XB + (size_t)NN * 256 * 2;
    const size_t OFF_BF   = OFF_WB + (size_t)256 * 256 * 2;
    const size_t OFF_ASF  = OFF_BF + 1024;
    const size_t OFF_ARF  = OFF_ASF + 1024;
    const size_t OFF_S    = OFF_ARF + 1024;
    const size_t OFF_R    = OFF_S + (size_t)NN * 4;
    const size_t OFF_GF   = OFF_R + (size_t)NN * 4;           // Gfrag, 1 MB
    const size_t OFF_ACC  = OFF_GF + (size_t)64 * NN * 2;
    const size_t OFF_DEN  = OFF_ACC + (size_t)4 * NN * 64 * 4;

    int*   flag = (int*)(ws + OFF_FLAG);
    short* Xb   = (short*)(ws + OFF_XB);
    short* Wb   = (short*)(ws + OFF_WB);
    float* bF   = (float*)(ws + OFF_BF);
    float* asF  = (float*)(ws + OFF_ASF);
    float* arF  = (float*)(ws + OFF_ARF);
    float* sP   = (float*)(ws + OFF_S);
    float* rP   = (float*)(ws + OFF_R);
    short* Gf   = (short*)(ws + OFF_GF);
    float* accP = (float*)(ws + OFF_ACC);
    float* denP = (float*)(ws + OFF_DEN);

    gat_probe_dtype<<<1, 256, 0, stream>>>((const unsigned short*)X, flag);
    gat_convert<<<512, 256, 0, stream>>>(X, W, bb, as_, ar_, Xb, Wb, bF, asF, arF, flag);
    gat_gemm1<<<NN / 32, 128, 0, stream>>>(Xb, Wb, bF, asF, arF, Gf, sP, rP);
    gat_pv6<<<(NN / 32) * 4, 256, 0, stream>>>(A, Gf, sP, rP, accP, denP);
    gat_final<<<NN * 16 / 256, 256, 0, stream>>>(accP, denP, flag, d_out);
}